// Round 4
// baseline (311.998 us; speedup 1.0000x reference)
//
#include <hip/hip_runtime.h>

// SoftDecisionTree (R9 resubmit — prior run died on container infra, not kernel):
//  gemm1: split-K 2->3 (22/22/20 K-steps), LDS 48 KB -> 3 blocks/CU,
//         B dbuf distance-1 + A reg distance-2, steady s_waitcnt vmcnt(8).
//  gemm2: counted-vmcnt dbuf pipeline (was drain-0 __syncthreads loop).
//   prep : Wb=bf16(W) padded, dT=softmax(leaf_params)^T
//   part = xs @ Wb^T (split-K=3, fp16 partials)    gemm1_kernel
//   lf   = tree(sigmoid(sum_s part + b))           reduce_tree_kernel (bf16 out)
//   out  = lf @ dT^T                               gemm2_kernel

typedef __bf16 bf16x8 __attribute__((ext_vector_type(8)));
typedef float f32x4 __attribute__((ext_vector_type(4)));
typedef _Float16 f16x8 __attribute__((ext_vector_type(8)));

#define B_DIM 8192
#define F_DIM 4096
#define NI 511
#define NL 512
#define K_DIM 1000
#define KPAD 1024
#define SPLIT 3

#define W_BLKS  1024        // 512*4096 / (256*8)
#define SM_BLKS 512

// RNE fp32->bf16 (prep / tree outputs)
__device__ inline unsigned short f2bf(float f) {
    unsigned int u = __float_as_uint(f);
    return (unsigned short)((u + 0x7FFFu + ((u >> 16) & 1u)) >> 16);
}
__device__ inline unsigned int pk_bf16(float a, float b) {
    return (unsigned int)f2bf(a) | ((unsigned int)f2bf(b) << 16);
}
// cheap round-half-up fp32 pair -> packed bf16x2 (2 adds + 1 perm)
__device__ inline unsigned int pk2_hu(float a, float b) {
    unsigned int ua = __float_as_uint(a) + 0x8000u;
    unsigned int ub = __float_as_uint(b) + 0x8000u;
    return __builtin_amdgcn_perm(ub, ua, 0x07060302u);
}

// async global->LDS, 16 B/lane; LDS dest = wave-uniform base + lane*16
typedef __attribute__((address_space(1))) const unsigned int guint;
typedef __attribute__((address_space(3))) unsigned int luint;
__device__ inline void gload16(const unsigned short* g, unsigned short* l) {
    __builtin_amdgcn_global_load_lds((guint*)g, (luint*)l, 16, 0, 0);
}

// swizzled bf16 fragment load: granule(16B) index ^= row&7  -> conflict-free
__device__ inline bf16x8 ldb(const unsigned short* Lbase, int r, int kb) {
    const int g = (kb >> 3) ^ (r & 7);
    return *(const bf16x8*)&Lbase[r * 64 + g * 8];
}

__device__ inline float waveMax(float v) {
#pragma unroll
    for (int off = 32; off; off >>= 1) v = fmaxf(v, __shfl_down(v, off, 64));
    return v;
}
__device__ inline float waveSum(float v) {
#pragma unroll
    for (int off = 32; off; off >>= 1) v += __shfl_down(v, off, 64);
    return v;
}

// ---------------- prep: W->bf16 (512-row pad), softmax^T ----------------
__global__ __launch_bounds__(256) void prep_kernel(
    const float* __restrict__ W, unsigned short* __restrict__ Wb,
    const float* __restrict__ lp, unsigned short* __restrict__ dT)
{
    __shared__ float sred[8];
    const int bid = blockIdx.x;
    const int tid = threadIdx.x;

    if (bid < W_BLKS) {
        const size_t i = ((size_t)bid * 256 + tid) * 8;
        const int row = (int)(i >> 12);  // /4096
        uint4 h = {0u, 0u, 0u, 0u};
        if (row < NI) {
            const float4 a = *(const float4*)(W + i);
            const float4 b = *(const float4*)(W + i + 4);
            h.x = pk_bf16(a.x, a.y);
            h.y = pk_bf16(a.z, a.w);
            h.z = pk_bf16(b.x, b.y);
            h.w = pk_bf16(b.z, b.w);
        }
        *(uint4*)(Wb + i) = h;
        return;
    }
    // softmax + transpose: dT[n][k] = softmax(leaf_params[k])[n]
    const int k = bid - W_BLKS;
    const int lane = tid & 63;
    const int wave = tid >> 6;
    const float* rowp = lp + (size_t)k * K_DIM;

    float vals[4];
    float mx = -3.0e38f;
#pragma unroll
    for (int c = 0; c < 4; ++c) {
        const int n = tid + c * 256;
        vals[c] = (n < K_DIM) ? rowp[n] : -3.0e38f;
        mx = fmaxf(mx, vals[c]);
    }
    mx = waveMax(mx);
    if (lane == 0) sred[wave] = mx;
    __syncthreads();
    const float gmax = fmaxf(fmaxf(sred[0], sred[1]), fmaxf(sred[2], sred[3]));

    float sum = 0.f;
#pragma unroll
    for (int c = 0; c < 4; ++c) {
        const int n = tid + c * 256;
        const float e = (n < K_DIM) ? __expf(vals[c] - gmax) : 0.f;
        vals[c] = e;
        sum += e;
    }
    sum = waveSum(sum);
    if (lane == 0) sred[4 + wave] = sum;
    __syncthreads();
    const float inv = 1.0f / (sred[4] + sred[5] + sred[6] + sred[7]);
#pragma unroll
    for (int c = 0; c < 4; ++c) {
        const int n = tid + c * 256;
        if (n < K_DIM) dT[(size_t)n * NL + k] = f2bf(vals[c] * inv);
    }
}

// ---------------- GEMM1: part[z] = xs @ Wb^T, counted-vmcnt, 3 blocks/CU ----------------
// grid 768 = 8 xcd x (8 mhi x 3 z x 4 nt); per XCD 96 blocks = 3/CU exactly.
// K split 22/22/20 steps of 64 (kbeg = z*1408).
// Per iter t: stage A(t) (cvt from regs) -> vmcnt(8 | 0 at last) -> barrier ->
//   issue B(t+1) gload_lds (buf PAR^1) -> issue A(t+2) reg loads -> compute(t) -> barrier.
// Wait math: at stage(t), reg-dep retires through A(t) leaving {B(t)4, A(t+1)8};
// vmcnt(8) retires B(t). Parity-unrolled loop keeps ab[]/Bl[] statically indexed.
__global__ __launch_bounds__(256, 3) void gemm1_kernel(
    const float* __restrict__ A, const unsigned short* __restrict__ Bb,
    _Float16* __restrict__ part)
{
    __shared__ __align__(16) unsigned short Al[128 * 64];        // 16 KB
    __shared__ __align__(16) unsigned short Bl[2][128 * 64];     // 32 KB dbuf

    const int id = blockIdx.x;
    const int xcd = id & 7;
    const int j = id >> 3;          // 0..95
    const int nt = j & 3;
    const int rem = j >> 2;         // 0..23 = mhi*3 + z
    const int mhi = rem / 3;        // 0..7
    const int z = rem - mhi * 3;    // 0..2
    const int m0 = (mhi * 8 + xcd) * 128;
    const int n0 = nt * 128;
    const int kbeg = z * 1408;
    const int NT = (z == 2) ? 20 : 22;   // always even

    const int tid = threadIdx.x;
    const int lane = tid & 63;
    const int wave = tid >> 6;
    const int wm = (wave >> 1) * 64;
    const int wn = (wave & 1) * 64;
    const int quad = lane >> 4;
    const int l16 = lane & 15;

    // A reg staging: row = wave*4 + (lane>>4) + p*16; q=lane&15 covers cols q*4..+3.
    const int rowA = wave * 4 + (lane >> 4);
    const int q = lane & 15;
    const float* gA = A + (size_t)(m0 + rowA) * F_DIM + kbeg + q * 4;

    // B staging (gload_lds): rows p*32 + wave*8 + (lane>>3); granule = (lane&7)^dr.
    const int drb = lane >> 3;
    const int cb = ((lane & 7) ^ drb) * 8;
    const unsigned short* gB = Bb + (size_t)(n0 + wave * 8 + drb) * F_DIM + kbeg + cb;
    const int lBoff = wave * 8 * 64;

    const f32x4 zero = {0.f, 0.f, 0.f, 0.f};
    f32x4 acc[4][4];
#pragma unroll
    for (int i = 0; i < 4; ++i)
#pragma unroll
        for (int j2 = 0; j2 < 4; ++j2) acc[i][j2] = zero;

    // ---- prologue: B(0) async into buf0; A(0),A(1) to regs ----
    f32x4 ab[2][8];
#pragma unroll
    for (int p = 0; p < 4; ++p)
        gload16(gB + (size_t)p * 32 * F_DIM, &Bl[0][lBoff + p * 2048]);
    __builtin_amdgcn_sched_barrier(0);
#pragma unroll
    for (int p = 0; p < 8; ++p)
        ab[0][p] = *(const f32x4*)(gA + (size_t)p * 16 * F_DIM);
#pragma unroll
    for (int p = 0; p < 8; ++p)
        ab[1][p] = *(const f32x4*)(gA + 64 + (size_t)p * 16 * F_DIM);
    __builtin_amdgcn_sched_barrier(0);

#define G1_ITER(TVAL, PAR)                                                     \
    {                                                                          \
        const int t_ = (TVAL);                                                 \
        _Pragma("unroll") for (int p = 0; p < 8; ++p) {                        \
            const int r = rowA + p * 16;                                       \
            uint2 w;                                                           \
            w.x = pk2_hu(ab[PAR][p].x, ab[PAR][p].y);                          \
            w.y = pk2_hu(ab[PAR][p].z, ab[PAR][p].w);                          \
            *(uint2*)&Al[r * 64 + (((q >> 1) ^ (r & 7)) * 8) + (q & 1) * 4] = w;\
        }                                                                      \
        if (t_ < NT - 1) {                                                     \
            asm volatile("s_waitcnt vmcnt(8) lgkmcnt(0)" ::: "memory");        \
        } else {                                                               \
            asm volatile("s_waitcnt vmcnt(0) lgkmcnt(0)" ::: "memory");        \
        }                                                                      \
        __builtin_amdgcn_sched_barrier(0);                                     \
        __builtin_amdgcn_s_barrier();                                          \
        __builtin_amdgcn_sched_barrier(0);                                     \
        if (t_ + 1 < NT) {                                                     \
            _Pragma("unroll") for (int p = 0; p < 4; ++p)                      \
                gload16(gB + (size_t)(t_ + 1) * 64 + (size_t)p * 32 * F_DIM,   \
                        &Bl[(PAR) ^ 1][lBoff + p * 2048]);                     \
        }                                                                      \
        __builtin_amdgcn_sched_barrier(0);                                     \
        if (t_ + 2 < NT) {                                                     \
            _Pragma("unroll") for (int p = 0; p < 8; ++p)                      \
                ab[PAR][p] = *(const f32x4*)(gA + (size_t)(t_ + 2) * 64        \
                                             + (size_t)p * 16 * F_DIM);       \
        }                                                                      \
        _Pragma("unroll") for (int kk = 0; kk < 64; kk += 32) {                \
            const int kb = kk + quad * 8;                                      \
            bf16x8 av[4], bv[4];                                               \
            _Pragma("unroll") for (int i = 0; i < 4; ++i)                      \
                av[i] = ldb(Al, wm + i * 16 + l16, kb);                        \
            _Pragma("unroll") for (int j2 = 0; j2 < 4; ++j2)                   \
                bv[j2] = ldb(&Bl[PAR][0], wn + j2 * 16 + l16, kb);             \
            _Pragma("unroll") for (int i = 0; i < 4; ++i)                      \
                _Pragma("unroll") for (int j2 = 0; j2 < 4; ++j2)               \
                    acc[i][j2] = __builtin_amdgcn_mfma_f32_16x16x32_bf16(      \
                        av[i], bv[j2], acc[i][j2], 0, 0, 0);                   \
        }                                                                      \
        __builtin_amdgcn_sched_barrier(0);                                     \
        __builtin_amdgcn_s_barrier();                                          \
        __builtin_amdgcn_sched_barrier(0);                                     \
    }

    for (int th = 0; th < NT / 2; ++th) {
        G1_ITER(2 * th, 0);
        G1_ITER(2 * th + 1, 1);
    }
#undef G1_ITER

    _Float16* dst = part + (size_t)z * ((size_t)B_DIM * NL);
#pragma unroll
    for (int i = 0; i < 4; ++i) {
        const int mbase = m0 + wm + i * 16 + quad * 4;
#pragma unroll
        for (int j2 = 0; j2 < 4; ++j2) {
            const int n = n0 + wn + j2 * 16 + l16;
#pragma unroll
            for (int r = 0; r < 4; ++r)
                dst[(size_t)(mbase + r) * NL + n] = (_Float16)acc[i][j2][r];
        }
    }
}

// ---------------- fused reduce(fp16 partials) + bias + sigmoid + tree ----------------
__global__ __launch_bounds__(256) void reduce_tree_kernel(
    const _Float16* __restrict__ part, const float* __restrict__ bvec,
    unsigned short* __restrict__ leafbf)
{
    __shared__ float bsh[NL];
    __shared__ float prow[4][NL];

    const int tid = threadIdx.x;
    bsh[tid] = (tid < NI) ? bvec[tid] : 0.0f;
    const int t2 = tid + 256;
    bsh[t2] = (t2 < NI) ? bvec[t2] : 0.0f;

    const int wave = tid >> 6;
    const int lane = tid & 63;
    const int row = blockIdx.x * 4 + wave;
    const size_t base = (size_t)row * NL + lane * 8;

    float v[8] = {0.f, 0.f, 0.f, 0.f, 0.f, 0.f, 0.f, 0.f};
#pragma unroll
    for (int s = 0; s < SPLIT; ++s) {
        const f16x8 h = *(const f16x8*)(part + (size_t)s * ((size_t)B_DIM * NL) + base);
#pragma unroll
        for (int e = 0; e < 8; ++e) v[e] += (float)h[e];
    }
    __syncthreads();

#pragma unroll
    for (int i = 0; i < 8; ++i) {
        const float x = v[i] + bsh[lane * 8 + i];
        prow[wave][lane * 8 + i] = 1.0f / (1.0f + __expf(-x));
    }
    __syncthreads();

    const float* pr = prow[wave];
    float pre = 1.0f;
    int pnode = 0;
#pragma unroll
    for (int t = 5; t >= 0; --t) {
        const int bit = (lane >> t) & 1;
        const float p = pr[pnode];
        pre *= bit ? p : (1.0f - p);
        pnode = 2 * pnode + 1 + bit;
    }
    unsigned short outs[8];
#pragma unroll
    for (int jj = 0; jj < 8; ++jj) {
        float prob = pre;
        int node = pnode;
#pragma unroll
        for (int t = 2; t >= 0; --t) {
            const int bit = (jj >> t) & 1;
            const float p = pr[node];
            prob *= bit ? p : (1.0f - p);
            node = 2 * node + 1 + bit;
        }
        outs[jj] = f2bf(prob);
    }
    uint4 r;
    r.x = (unsigned int)outs[0] | ((unsigned int)outs[1] << 16);
    r.y = (unsigned int)outs[2] | ((unsigned int)outs[3] << 16);
    r.z = (unsigned int)outs[4] | ((unsigned int)outs[5] << 16);
    r.w = (unsigned int)outs[6] | ((unsigned int)outs[7] << 16);
    *(uint4*)(leafbf + (size_t)row * NL + lane * 8) = r;
}

// ---------------- GEMM2: out = leaf_prob @ dists, counted-vmcnt dbuf ----------------
// grid 512 = 8 xcd x 8 mhi x 8 nt; 64 KB LDS -> 2 blocks/CU even.
// Per iter: issue(t+1) -> vmcnt(8|0) -> barrier -> compute(t) -> barrier.
__global__ __launch_bounds__(256, 2) void gemm2_kernel(
    const unsigned short* __restrict__ A, const unsigned short* __restrict__ Bm,
    float* __restrict__ out)
{
    __shared__ __align__(16) unsigned short Al[2][128 * 64];    // 32 KB
    __shared__ __align__(16) unsigned short Bl[2][128 * 64];    // 32 KB

    const int id = blockIdx.x;
    const int xcd = id & 7;
    const int j = id >> 3;
    const int nt = j & 7;
    const int mhi = j >> 3;
    const int m0 = (mhi * 8 + xcd) * 128;
    const int n0 = nt * 128;

    const int tid = threadIdx.x;
    const int lane = tid & 63;
    const int wave = tid >> 6;
    const int wm = (wave >> 1) * 64;
    const int wn = (wave & 1) * 64;
    const int quad = lane >> 4;
    const int l16 = lane & 15;

    const int drb = lane >> 3;
    const int cb = ((lane & 7) ^ drb) * 8;
    const unsigned short* gA = A + (size_t)(m0 + wave * 8 + drb) * NL + cb;
    const unsigned short* gB = Bm + (size_t)(n0 + wave * 8 + drb) * NL + cb;
    const int loff = wave * 8 * 64;

    const f32x4 zero = {0.f, 0.f, 0.f, 0.f};
    f32x4 acc[4][4];
#pragma unroll
    for (int i = 0; i < 4; ++i)
#pragma unroll
        for (int j2 = 0; j2 < 4; ++j2) acc[i][j2] = zero;

    // prologue: issue tile 0
#pragma unroll
    for (int p = 0; p < 4; ++p) {
        gload16(gA + (size_t)p * 32 * NL, &Al[0][loff + p * 2048]);
        gload16(gB + (size_t)p * 32 * NL, &Bl[0][loff + p * 2048]);
    }
    __builtin_amdgcn_sched_barrier(0);

#pragma unroll
    for (int t = 0; t < 8; ++t) {
        if (t + 1 < 8) {
#pragma unroll
            for (int p = 0; p < 4; ++p) {
                gload16(gA + (size_t)(t + 1) * 64 + (size_t)p * 32 * NL,
                        &Al[(t + 1) & 1][loff + p * 2048]);
                gload16(gB + (size_t)(t + 1) * 64 + (size_t)p * 32 * NL,
                        &Bl[(t + 1) & 1][loff + p * 2048]);
            }
            __builtin_amdgcn_sched_barrier(0);
            asm volatile("s_waitcnt vmcnt(8)" ::: "memory");
        } else {
            __builtin_amdgcn_sched_barrier(0);
            asm volatile("s_waitcnt vmcnt(0)" ::: "memory");
        }
        __builtin_amdgcn_sched_barrier(0);
        __builtin_amdgcn_s_barrier();
        __builtin_amdgcn_sched_barrier(0);
#pragma unroll
        for (int kk = 0; kk < 64; kk += 32) {
            const int kb = kk + quad * 8;
            bf16x8 av[4], bv[4];
#pragma unroll
            for (int i = 0; i < 4; ++i)
                av[i] = ldb(&Al[t & 1][0], wm + i * 16 + l16, kb);
#pragma unroll
            for (int j2 = 0; j2 < 4; ++j2)
                bv[j2] = ldb(&Bl[t & 1][0], wn + j2 * 16 + l16, kb);
#pragma unroll
            for (int i = 0; i < 4; ++i)
#pragma unroll
                for (int j2 = 0; j2 < 4; ++j2)
                    acc[i][j2] = __builtin_amdgcn_mfma_f32_16x16x32_bf16(av[i], bv[j2], acc[i][j2], 0, 0, 0);
        }
        __builtin_amdgcn_sched_barrier(0);
        __builtin_amdgcn_s_barrier();
        __builtin_amdgcn_sched_barrier(0);
    }

#pragma unroll
    for (int i = 0; i < 4; ++i) {
        const int mbase = m0 + wm + i * 16 + quad * 4;
#pragma unroll
        for (int j2 = 0; j2 < 4; ++j2) {
            const int n = n0 + wn + j2 * 16 + l16;
            if (n < K_DIM) {
#pragma unroll
                for (int r = 0; r < 4; ++r)
                    out[(size_t)(mbase + r) * K_DIM + n] = acc[i][j2][r];
            }
        }
    }
}

extern "C" void kernel_launch(void* const* d_in, const int* in_sizes, int n_in,
                              void* d_out, int out_size, void* d_ws, size_t ws_size,
                              hipStream_t stream) {
    const float* xs = (const float*)d_in[0];
    const float* W  = (const float*)d_in[1];
    const float* b  = (const float*)d_in[2];
    const float* lp = (const float*)d_in[3];
    float* out = (float*)d_out;

    const size_t partB = (size_t)B_DIM * NL * 2;   //  8 MiB per slice (fp16)
    const size_t leafB = (size_t)B_DIM * NL * 2;   //  8 MiB
    const size_t dTB   = (size_t)KPAD * NL * 2;    //  1 MiB

    char* ws = (char*)d_ws;
    _Float16* part = (_Float16*)ws;
    unsigned short* leafbf = (unsigned short*)(ws + SPLIT * partB);
    unsigned short* dT = (unsigned short*)(ws + SPLIT * partB + leafB);
    unsigned short* Wb = (unsigned short*)(ws + SPLIT * partB + leafB + dTB);
    (void)ws_size;  // needs ~37 MiB; harness provides 512 MiB

    hipLaunchKernelGGL(prep_kernel, dim3(W_BLKS + SM_BLKS), dim3(256), 0, stream,
                       W, Wb, lp, dT);
    hipLaunchKernelGGL(gemm1_kernel, dim3(768), dim3(256), 0, stream,
                       xs, Wb, part);
    hipLaunchKernelGGL(reduce_tree_kernel, dim3(B_DIM / 4), dim3(256), 0, stream,
                       part, b, leafbf);
    hipLaunchKernelGGL(gemm2_kernel, dim3(8 * 8 * 8), dim3(256), 0, stream,
                       leafbf, dT, out);
}

// Round 6
// 264.767 us; speedup vs baseline: 1.1784x; 1.1784x over previous
//
#include <hip/hip_runtime.h>

// SoftDecisionTree (R10 resubmit — prior run died on container infra; R9 precedent:
// same error, identical source passed on resubmit).
//  gemm1: 3 blocks/CU pinned via amdgpu_waves_per_eu(3,3); A-pipeline split into
//         abf[8] (fp32 in-flight) + abh[8] (bf16 staged) = 48 regs (was 64);
//         stage phase is pure ds_write (no reg-dep); counted s_waitcnt vmcnt(8).
//  gemm2: counted-vmcnt dbuf pipeline.
//   prep : Wb=bf16(W) padded, dT=softmax(leaf_params)^T
//   part = xs @ Wb^T (split-K=3, fp16 partials)    gemm1_kernel
//   lf   = tree(sigmoid(sum_s part + b))           reduce_tree_kernel (bf16 out)
//   out  = lf @ dT^T                               gemm2_kernel

typedef __bf16 bf16x8 __attribute__((ext_vector_type(8)));
typedef float f32x4 __attribute__((ext_vector_type(4)));
typedef _Float16 f16x8 __attribute__((ext_vector_type(8)));

#define B_DIM 8192
#define F_DIM 4096
#define NI 511
#define NL 512
#define K_DIM 1000
#define KPAD 1024
#define SPLIT 3

#define W_BLKS  1024        // 512*4096 / (256*8)
#define SM_BLKS 512

// RNE fp32->bf16 (prep / tree outputs)
__device__ inline unsigned short f2bf(float f) {
    unsigned int u = __float_as_uint(f);
    return (unsigned short)((u + 0x7FFFu + ((u >> 16) & 1u)) >> 16);
}
__device__ inline unsigned int pk_bf16(float a, float b) {
    return (unsigned int)f2bf(a) | ((unsigned int)f2bf(b) << 16);
}
// cheap round-half-up fp32 pair -> packed bf16x2 (2 adds + 1 perm)
__device__ inline unsigned int pk2_hu(float a, float b) {
    unsigned int ua = __float_as_uint(a) + 0x8000u;
    unsigned int ub = __float_as_uint(b) + 0x8000u;
    return __builtin_amdgcn_perm(ub, ua, 0x07060302u);
}

// async global->LDS, 16 B/lane; LDS dest = wave-uniform base + lane*16
typedef __attribute__((address_space(1))) const unsigned int guint;
typedef __attribute__((address_space(3))) unsigned int luint;
__device__ inline void gload16(const unsigned short* g, unsigned short* l) {
    __builtin_amdgcn_global_load_lds((guint*)g, (luint*)l, 16, 0, 0);
}

// swizzled bf16 fragment load: granule(16B) index ^= row&7  -> conflict-free
__device__ inline bf16x8 ldb(const unsigned short* Lbase, int r, int kb) {
    const int g = (kb >> 3) ^ (r & 7);
    return *(const bf16x8*)&Lbase[r * 64 + g * 8];
}

__device__ inline float waveMax(float v) {
#pragma unroll
    for (int off = 32; off; off >>= 1) v = fmaxf(v, __shfl_down(v, off, 64));
    return v;
}
__device__ inline float waveSum(float v) {
#pragma unroll
    for (int off = 32; off; off >>= 1) v += __shfl_down(v, off, 64);
    return v;
}

// ---------------- prep: W->bf16 (512-row pad), softmax^T ----------------
__global__ __launch_bounds__(256) void prep_kernel(
    const float* __restrict__ W, unsigned short* __restrict__ Wb,
    const float* __restrict__ lp, unsigned short* __restrict__ dT)
{
    __shared__ float sred[8];
    const int bid = blockIdx.x;
    const int tid = threadIdx.x;

    if (bid < W_BLKS) {
        const size_t i = ((size_t)bid * 256 + tid) * 8;
        const int row = (int)(i >> 12);  // /4096
        uint4 h = {0u, 0u, 0u, 0u};
        if (row < NI) {
            const float4 a = *(const float4*)(W + i);
            const float4 b = *(const float4*)(W + i + 4);
            h.x = pk_bf16(a.x, a.y);
            h.y = pk_bf16(a.z, a.w);
            h.z = pk_bf16(b.x, b.y);
            h.w = pk_bf16(b.z, b.w);
        }
        *(uint4*)(Wb + i) = h;
        return;
    }
    // softmax + transpose: dT[n][k] = softmax(leaf_params[k])[n]
    const int k = bid - W_BLKS;
    const int lane = tid & 63;
    const int wave = tid >> 6;
    const float* rowp = lp + (size_t)k * K_DIM;

    float vals[4];
    float mx = -3.0e38f;
#pragma unroll
    for (int c = 0; c < 4; ++c) {
        const int n = tid + c * 256;
        vals[c] = (n < K_DIM) ? rowp[n] : -3.0e38f;
        mx = fmaxf(mx, vals[c]);
    }
    mx = waveMax(mx);
    if (lane == 0) sred[wave] = mx;
    __syncthreads();
    const float gmax = fmaxf(fmaxf(sred[0], sred[1]), fmaxf(sred[2], sred[3]));

    float sum = 0.f;
#pragma unroll
    for (int c = 0; c < 4; ++c) {
        const int n = tid + c * 256;
        const float e = (n < K_DIM) ? __expf(vals[c] - gmax) : 0.f;
        vals[c] = e;
        sum += e;
    }
    sum = waveSum(sum);
    if (lane == 0) sred[4 + wave] = sum;
    __syncthreads();
    const float inv = 1.0f / (sred[4] + sred[5] + sred[6] + sred[7]);
#pragma unroll
    for (int c = 0; c < 4; ++c) {
        const int n = tid + c * 256;
        if (n < K_DIM) dT[(size_t)n * NL + k] = f2bf(vals[c] * inv);
    }
}

// ---------------- GEMM1: part[z] = xs @ Wb^T, counted-vmcnt, 3 blocks/CU ----------------
// grid 768 = 8 xcd x (8 mhi x 3 z x 4 nt); per XCD 96 blocks = 3/CU exactly.
// K split 22/22/20 steps of 64 (kbeg = z*1408). LDS 48 KB; waves_per_eu pinned (3,3).
// Registers: abf[8] fp32 in-flight (32) + abh[8] bf16 staged (16) + acc 64 (AGPR).
// Per iter t:
//   S : ds_write Al <- abh (A(t), bf16)  [pure reg->LDS, no reg-dep]
//   W : s_waitcnt vmcnt(8) lgkmcnt(0)    [queue = {B(t)4, A(t+1)8}; retires B(t)]
//   barrier
//   I1: issue B(t+1) gload_lds -> Bl[(t+1)&1]
//   I2: abh <- cvt(abf) = A(t+1)         [reg-dep retires A(t+1) only, B(t+1) stays]
//   I3: issue A(t+2) -> abf
//   C : 32 MFMA from Al, Bl[t&1]
//   barrier
__global__ __launch_bounds__(256) __attribute__((amdgpu_waves_per_eu(3, 3)))
void gemm1_kernel(
    const float* __restrict__ A, const unsigned short* __restrict__ Bb,
    _Float16* __restrict__ part)
{
    __shared__ __align__(16) unsigned short Al[128 * 64];        // 16 KB
    __shared__ __align__(16) unsigned short Bl[2][128 * 64];     // 32 KB dbuf

    const int id = blockIdx.x;
    const int xcd = id & 7;
    const int j = id >> 3;          // 0..95
    const int nt = j & 3;
    const int rem = j >> 2;         // 0..23 = mhi*3 + z
    const int mhi = rem / 3;        // 0..7
    const int z = rem - mhi * 3;    // 0..2
    const int m0 = (mhi * 8 + xcd) * 128;
    const int n0 = nt * 128;
    const int kbeg = z * 1408;
    const int NT = (z == 2) ? 20 : 22;

    const int tid = threadIdx.x;
    const int lane = tid & 63;
    const int wave = tid >> 6;
    const int wm = (wave >> 1) * 64;
    const int wn = (wave & 1) * 64;
    const int quad = lane >> 4;
    const int l16 = lane & 15;

    // A reg staging: row = wave*4 + (lane>>4) + p*16; q=lane&15 covers cols q*4..+3.
    const int rowA = wave * 4 + (lane >> 4);
    const int q = lane & 15;
    const float* gA = A + (size_t)(m0 + rowA) * F_DIM + kbeg + q * 4;
    // LDS write slot (swizzled): granule (q>>1)^(r&7), half q&1
    unsigned short* lw[8];
#pragma unroll
    for (int p = 0; p < 8; ++p) {
        const int r = rowA + p * 16;
        lw[p] = &Al[r * 64 + (((q >> 1) ^ (r & 7)) * 8) + (q & 1) * 4];
    }

    // B staging (gload_lds): rows p*32 + wave*8 + (lane>>3); granule = (lane&7)^dr.
    const int drb = lane >> 3;
    const int cb = ((lane & 7) ^ drb) * 8;
    const unsigned short* gB = Bb + (size_t)(n0 + wave * 8 + drb) * F_DIM + kbeg + cb;
    const int lBoff = wave * 8 * 64;

    const f32x4 zero = {0.f, 0.f, 0.f, 0.f};
    f32x4 acc[4][4];
#pragma unroll
    for (int i = 0; i < 4; ++i)
#pragma unroll
        for (int j2 = 0; j2 < 4; ++j2) acc[i][j2] = zero;

    f32x4 abf[8];     // fp32 A tile in flight
    uint2 abh[8];     // bf16 A tile, staged next

    // ---- prologue ----
#pragma unroll
    for (int p = 0; p < 4; ++p)
        gload16(gB + (size_t)p * 32 * F_DIM, &Bl[0][lBoff + p * 2048]);
    __builtin_amdgcn_sched_barrier(0);
#pragma unroll
    for (int p = 0; p < 8; ++p)
        abf[p] = *(const f32x4*)(gA + (size_t)p * 16 * F_DIM);
    __builtin_amdgcn_sched_barrier(0);
#pragma unroll
    for (int p = 0; p < 8; ++p) {      // cvt A(0); reg-dep drains B(0),A(0) (prologue only)
        abh[p].x = pk2_hu(abf[p].x, abf[p].y);
        abh[p].y = pk2_hu(abf[p].z, abf[p].w);
    }
#pragma unroll
    for (int p = 0; p < 8; ++p)        // issue A(1)
        abf[p] = *(const f32x4*)(gA + 64 + (size_t)p * 16 * F_DIM);
    __builtin_amdgcn_sched_barrier(0);

    for (int t = 0; t < NT; ++t) {
        // S: stage A(t) from abh (pure ds_write)
#pragma unroll
        for (int p = 0; p < 8; ++p)
            *(uint2*)lw[p] = abh[p];
        // W
        if (t < NT - 1) {
            asm volatile("s_waitcnt vmcnt(8) lgkmcnt(0)" ::: "memory");
        } else {
            asm volatile("s_waitcnt vmcnt(0) lgkmcnt(0)" ::: "memory");
        }
        __builtin_amdgcn_sched_barrier(0);
        __builtin_amdgcn_s_barrier();
        __builtin_amdgcn_sched_barrier(0);
        // I1: issue B(t+1)
        if (t + 1 < NT) {
#pragma unroll
            for (int p = 0; p < 4; ++p)
                gload16(gB + (size_t)(t + 1) * 64 + (size_t)p * 32 * F_DIM,
                        &Bl[(t + 1) & 1][lBoff + p * 2048]);
        }
        __builtin_amdgcn_sched_barrier(0);
        // I2: cvt A(t+1) (arrived ~1 iter ago); I3: issue A(t+2)
        if (t + 1 < NT) {
#pragma unroll
            for (int p = 0; p < 8; ++p) {
                abh[p].x = pk2_hu(abf[p].x, abf[p].y);
                abh[p].y = pk2_hu(abf[p].z, abf[p].w);
            }
        }
        if (t + 2 < NT) {
#pragma unroll
            for (int p = 0; p < 8; ++p)
                abf[p] = *(const f32x4*)(gA + (size_t)(t + 2) * 64
                                         + (size_t)p * 16 * F_DIM);
        }
        __builtin_amdgcn_sched_barrier(0);
        // C: compute tile t
        const unsigned short* Bcur = &Bl[t & 1][0];
#pragma unroll
        for (int kk = 0; kk < 64; kk += 32) {
            const int kb = kk + quad * 8;
            bf16x8 av[4], bv[4];
#pragma unroll
            for (int i = 0; i < 4; ++i)
                av[i] = ldb(Al, wm + i * 16 + l16, kb);
#pragma unroll
            for (int j2 = 0; j2 < 4; ++j2)
                bv[j2] = ldb(Bcur, wn + j2 * 16 + l16, kb);
#pragma unroll
            for (int i = 0; i < 4; ++i)
#pragma unroll
                for (int j2 = 0; j2 < 4; ++j2)
                    acc[i][j2] = __builtin_amdgcn_mfma_f32_16x16x32_bf16(
                        av[i], bv[j2], acc[i][j2], 0, 0, 0);
        }
        __builtin_amdgcn_sched_barrier(0);
        __builtin_amdgcn_s_barrier();
        __builtin_amdgcn_sched_barrier(0);
    }

    _Float16* dst = part + (size_t)z * ((size_t)B_DIM * NL);
#pragma unroll
    for (int i = 0; i < 4; ++i) {
        const int mbase = m0 + wm + i * 16 + quad * 4;
#pragma unroll
        for (int j2 = 0; j2 < 4; ++j2) {
            const int n = n0 + wn + j2 * 16 + l16;
#pragma unroll
            for (int r = 0; r < 4; ++r)
                dst[(size_t)(mbase + r) * NL + n] = (_Float16)acc[i][j2][r];
        }
    }
}

// ---------------- fused reduce(fp16 partials) + bias + sigmoid + tree ----------------
__global__ __launch_bounds__(256) void reduce_tree_kernel(
    const _Float16* __restrict__ part, const float* __restrict__ bvec,
    unsigned short* __restrict__ leafbf)
{
    __shared__ float bsh[NL];
    __shared__ float prow[4][NL];

    const int tid = threadIdx.x;
    bsh[tid] = (tid < NI) ? bvec[tid] : 0.0f;
    const int t2 = tid + 256;
    bsh[t2] = (t2 < NI) ? bvec[t2] : 0.0f;

    const int wave = tid >> 6;
    const int lane = tid & 63;
    const int row = blockIdx.x * 4 + wave;
    const size_t base = (size_t)row * NL + lane * 8;

    float v[8] = {0.f, 0.f, 0.f, 0.f, 0.f, 0.f, 0.f, 0.f};
#pragma unroll
    for (int s = 0; s < SPLIT; ++s) {
        const f16x8 h = *(const f16x8*)(part + (size_t)s * ((size_t)B_DIM * NL) + base);
#pragma unroll
        for (int e = 0; e < 8; ++e) v[e] += (float)h[e];
    }
    __syncthreads();

#pragma unroll
    for (int i = 0; i < 8; ++i) {
        const float x = v[i] + bsh[lane * 8 + i];
        prow[wave][lane * 8 + i] = 1.0f / (1.0f + __expf(-x));
    }
    __syncthreads();

    const float* pr = prow[wave];
    float pre = 1.0f;
    int pnode = 0;
#pragma unroll
    for (int t = 5; t >= 0; --t) {
        const int bit = (lane >> t) & 1;
        const float p = pr[pnode];
        pre *= bit ? p : (1.0f - p);
        pnode = 2 * pnode + 1 + bit;
    }
    unsigned short outs[8];
#pragma unroll
    for (int jj = 0; jj < 8; ++jj) {
        float prob = pre;
        int node = pnode;
#pragma unroll
        for (int t = 2; t >= 0; --t) {
            const int bit = (jj >> t) & 1;
            const float p = pr[node];
            prob *= bit ? p : (1.0f - p);
            node = 2 * node + 1 + bit;
        }
        outs[jj] = f2bf(prob);
    }
    uint4 r;
    r.x = (unsigned int)outs[0] | ((unsigned int)outs[1] << 16);
    r.y = (unsigned int)outs[2] | ((unsigned int)outs[3] << 16);
    r.z = (unsigned int)outs[4] | ((unsigned int)outs[5] << 16);
    r.w = (unsigned int)outs[6] | ((unsigned int)outs[7] << 16);
    *(uint4*)(leafbf + (size_t)row * NL + lane * 8) = r;
}

// ---------------- GEMM2: out = leaf_prob @ dists, counted-vmcnt dbuf ----------------
// grid 512 = 8 xcd x 8 mhi x 8 nt; 64 KB LDS -> 2 blocks/CU even.
// Per iter: issue(t+1) -> vmcnt(8|0) -> barrier -> compute(t) -> barrier.
__global__ __launch_bounds__(256, 2) void gemm2_kernel(
    const unsigned short* __restrict__ A, const unsigned short* __restrict__ Bm,
    float* __restrict__ out)
{
    __shared__ __align__(16) unsigned short Al[2][128 * 64];    // 32 KB
    __shared__ __align__(16) unsigned short Bl[2][128 * 64];    // 32 KB

    const int id = blockIdx.x;
    const int xcd = id & 7;
    const int j = id >> 3;
    const int nt = j & 7;
    const int mhi = j >> 3;
    const int m0 = (mhi * 8 + xcd) * 128;
    const int n0 = nt * 128;

    const int tid = threadIdx.x;
    const int lane = tid & 63;
    const int wave = tid >> 6;
    const int wm = (wave >> 1) * 64;
    const int wn = (wave & 1) * 64;
    const int quad = lane >> 4;
    const int l16 = lane & 15;

    const int drb = lane >> 3;
    const int cb = ((lane & 7) ^ drb) * 8;
    const unsigned short* gA = A + (size_t)(m0 + wave * 8 + drb) * NL + cb;
    const unsigned short* gB = Bm + (size_t)(n0 + wave * 8 + drb) * NL + cb;
    const int loff = wave * 8 * 64;

    const f32x4 zero = {0.f, 0.f, 0.f, 0.f};
    f32x4 acc[4][4];
#pragma unroll
    for (int i = 0; i < 4; ++i)
#pragma unroll
        for (int j2 = 0; j2 < 4; ++j2) acc[i][j2] = zero;

    // prologue: issue tile 0
#pragma unroll
    for (int p = 0; p < 4; ++p) {
        gload16(gA + (size_t)p * 32 * NL, &Al[0][loff + p * 2048]);
        gload16(gB + (size_t)p * 32 * NL, &Bl[0][loff + p * 2048]);
    }
    __builtin_amdgcn_sched_barrier(0);

#pragma unroll
    for (int t = 0; t < 8; ++t) {
        if (t + 1 < 8) {
#pragma unroll
            for (int p = 0; p < 4; ++p) {
                gload16(gA + (size_t)(t + 1) * 64 + (size_t)p * 32 * NL,
                        &Al[(t + 1) & 1][loff + p * 2048]);
                gload16(gB + (size_t)(t + 1) * 64 + (size_t)p * 32 * NL,
                        &Bl[(t + 1) & 1][loff + p * 2048]);
            }
            __builtin_amdgcn_sched_barrier(0);
            asm volatile("s_waitcnt vmcnt(8)" ::: "memory");
        } else {
            __builtin_amdgcn_sched_barrier(0);
            asm volatile("s_waitcnt vmcnt(0)" ::: "memory");
        }
        __builtin_amdgcn_sched_barrier(0);
        __builtin_amdgcn_s_barrier();
        __builtin_amdgcn_sched_barrier(0);
#pragma unroll
        for (int kk = 0; kk < 64; kk += 32) {
            const int kb = kk + quad * 8;
            bf16x8 av[4], bv[4];
#pragma unroll
            for (int i = 0; i < 4; ++i)
                av[i] = ldb(&Al[t & 1][0], wm + i * 16 + l16, kb);
#pragma unroll
            for (int j2 = 0; j2 < 4; ++j2)
                bv[j2] = ldb(&Bl[t & 1][0], wn + j2 * 16 + l16, kb);
#pragma unroll
            for (int i = 0; i < 4; ++i)
#pragma unroll
                for (int j2 = 0; j2 < 4; ++j2)
                    acc[i][j2] = __builtin_amdgcn_mfma_f32_16x16x32_bf16(av[i], bv[j2], acc[i][j2], 0, 0, 0);
        }
        __builtin_amdgcn_sched_barrier(0);
        __builtin_amdgcn_s_barrier();
        __builtin_amdgcn_sched_barrier(0);
    }

#pragma unroll
    for (int i = 0; i < 4; ++i) {
        const int mbase = m0 + wm + i * 16 + quad * 4;
#pragma unroll
        for (int j2 = 0; j2 < 4; ++j2) {
            const int n = n0 + wn + j2 * 16 + l16;
            if (n < K_DIM) {
#pragma unroll
                for (int r = 0; r < 4; ++r)
                    out[(size_t)(mbase + r) * K_DIM + n] = acc[i][j2][r];
            }
        }
    }
}

extern "C" void kernel_launch(void* const* d_in, const int* in_sizes, int n_in,
                              void* d_out, int out_size, void* d_ws, size_t ws_size,
                              hipStream_t stream) {
    const float* xs = (const float*)d_in[0];
    const float* W  = (const float*)d_in[1];
    const float* b  = (const float*)d_in[2];
    const float* lp = (const float*)d_in[3];
    float* out = (float*)d_out;

    const size_t partB = (size_t)B_DIM * NL * 2;   //  8 MiB per slice (fp16)
    const size_t leafB = (size_t)B_DIM * NL * 2;   //  8 MiB
    const size_t dTB   = (size_t)KPAD * NL * 2;    //  1 MiB

    char* ws = (char*)d_ws;
    _Float16* part = (_Float16*)ws;
    unsigned short* leafbf = (unsigned short*)(ws + SPLIT * partB);
    unsigned short* dT = (unsigned short*)(ws + SPLIT * partB + leafB);
    unsigned short* Wb = (unsigned short*)(ws + SPLIT * partB + leafB + dTB);
    (void)ws_size;  // needs ~37 MiB; harness provides 512 MiB

    hipLaunchKernelGGL(prep_kernel, dim3(W_BLKS + SM_BLKS), dim3(256), 0, stream,
                       W, Wb, lp, dT);
    hipLaunchKernelGGL(gemm1_kernel, dim3(768), dim3(256), 0, stream,
                       xs, Wb, part);
    hipLaunchKernelGGL(reduce_tree_kernel, dim3(B_DIM / 4), dim3(256), 0, stream,
                       part, b, leafbf);
    hipLaunchKernelGGL(gemm2_kernel, dim3(8 * 8 * 8), dim3(256), 0, stream,
                       leafbf, dT, out);
}

// Round 7
// 258.864 us; speedup vs baseline: 1.2053x; 1.0228x over previous
//
#include <hip/hip_runtime.h>

// SoftDecisionTree (R11): kill gemm1's A re-reads.
//  gemm1: 128m x 512n (full-N) blocks, 512 thr / 8 waves, split-K=4, grid 256
//         = 1 block/CU. Each fp32 A-chunk read by exactly ONE block
//         (A traffic 553 -> 134 MB). B dbuf 2x64KB in LDS (L2-resident),
//         counted s_waitcnt vmcnt(4); A reg-pipeline distance 2 (abf/abh).
//  gemm2: counted-vmcnt dbuf pipeline (unchanged).
//   prep : Wb=bf16(W) padded, dT=softmax(leaf_params)^T
//   part = xs @ Wb^T (split-K=4, fp16 partials)    gemm1_kernel
//   lf   = tree(sigmoid(sum_s part + b))           reduce_tree_kernel (bf16 out)
//   out  = lf @ dT^T                               gemm2_kernel

typedef __bf16 bf16x8 __attribute__((ext_vector_type(8)));
typedef float f32x4 __attribute__((ext_vector_type(4)));
typedef _Float16 f16x8 __attribute__((ext_vector_type(8)));

#define B_DIM 8192
#define F_DIM 4096
#define NI 511
#define NL 512
#define K_DIM 1000
#define KPAD 1024
#define SPLIT 4

#define W_BLKS  1024        // 512*4096 / (256*8)
#define SM_BLKS 512

// RNE fp32->bf16 (prep / tree outputs)
__device__ inline unsigned short f2bf(float f) {
    unsigned int u = __float_as_uint(f);
    return (unsigned short)((u + 0x7FFFu + ((u >> 16) & 1u)) >> 16);
}
__device__ inline unsigned int pk_bf16(float a, float b) {
    return (unsigned int)f2bf(a) | ((unsigned int)f2bf(b) << 16);
}
// cheap round-half-up fp32 pair -> packed bf16x2 (2 adds + 1 perm)
__device__ inline unsigned int pk2_hu(float a, float b) {
    unsigned int ua = __float_as_uint(a) + 0x8000u;
    unsigned int ub = __float_as_uint(b) + 0x8000u;
    return __builtin_amdgcn_perm(ub, ua, 0x07060302u);
}

// async global->LDS, 16 B/lane; LDS dest = wave-uniform base + lane*16
typedef __attribute__((address_space(1))) const unsigned int guint;
typedef __attribute__((address_space(3))) unsigned int luint;
__device__ inline void gload16(const unsigned short* g, unsigned short* l) {
    __builtin_amdgcn_global_load_lds((guint*)g, (luint*)l, 16, 0, 0);
}

// swizzled bf16 fragment load: granule(16B) index ^= row&7  -> conflict-free
__device__ inline bf16x8 ldb(const unsigned short* Lbase, int r, int kb) {
    const int g = (kb >> 3) ^ (r & 7);
    return *(const bf16x8*)&Lbase[r * 64 + g * 8];
}

__device__ inline float waveMax(float v) {
#pragma unroll
    for (int off = 32; off; off >>= 1) v = fmaxf(v, __shfl_down(v, off, 64));
    return v;
}
__device__ inline float waveSum(float v) {
#pragma unroll
    for (int off = 32; off; off >>= 1) v += __shfl_down(v, off, 64);
    return v;
}

// ---------------- prep: W->bf16 (512-row pad), softmax^T ----------------
__global__ __launch_bounds__(256) void prep_kernel(
    const float* __restrict__ W, unsigned short* __restrict__ Wb,
    const float* __restrict__ lp, unsigned short* __restrict__ dT)
{
    __shared__ float sred[8];
    const int bid = blockIdx.x;
    const int tid = threadIdx.x;

    if (bid < W_BLKS) {
        const size_t i = ((size_t)bid * 256 + tid) * 8;
        const int row = (int)(i >> 12);  // /4096
        uint4 h = {0u, 0u, 0u, 0u};
        if (row < NI) {
            const float4 a = *(const float4*)(W + i);
            const float4 b = *(const float4*)(W + i + 4);
            h.x = pk_bf16(a.x, a.y);
            h.y = pk_bf16(a.z, a.w);
            h.z = pk_bf16(b.x, b.y);
            h.w = pk_bf16(b.z, b.w);
        }
        *(uint4*)(Wb + i) = h;
        return;
    }
    // softmax + transpose: dT[n][k] = softmax(leaf_params[k])[n]
    const int k = bid - W_BLKS;
    const int lane = tid & 63;
    const int wave = tid >> 6;
    const float* rowp = lp + (size_t)k * K_DIM;

    float vals[4];
    float mx = -3.0e38f;
#pragma unroll
    for (int c = 0; c < 4; ++c) {
        const int n = tid + c * 256;
        vals[c] = (n < K_DIM) ? rowp[n] : -3.0e38f;
        mx = fmaxf(mx, vals[c]);
    }
    mx = waveMax(mx);
    if (lane == 0) sred[wave] = mx;
    __syncthreads();
    const float gmax = fmaxf(fmaxf(sred[0], sred[1]), fmaxf(sred[2], sred[3]));

    float sum = 0.f;
#pragma unroll
    for (int c = 0; c < 4; ++c) {
        const int n = tid + c * 256;
        const float e = (n < K_DIM) ? __expf(vals[c] - gmax) : 0.f;
        vals[c] = e;
        sum += e;
    }
    sum = waveSum(sum);
    if (lane == 0) sred[4 + wave] = sum;
    __syncthreads();
    const float inv = 1.0f / (sred[4] + sred[5] + sred[6] + sred[7]);
#pragma unroll
    for (int c = 0; c < 4; ++c) {
        const int n = tid + c * 256;
        if (n < K_DIM) dT[(size_t)n * NL + k] = f2bf(vals[c] * inv);
    }
}

// ---------------- GEMM1: part[z] = xs @ Wb^T, full-N blocks, 1/CU ----------------
// grid 256 = 8 xcd x 32; mt = xcd*8 + (g>>2), z = g&3; K-chunk 1024 (16 steps).
// Per iter t:
//   S : ds_write Al <- abh (A(t), bf16)
//   W : s_waitcnt vmcnt(4)  [queue = {B(t)8, A(t+1)4}; retires B(t)]   (0 at last)
//   barrier
//   I1: issue B(t+1) gload_lds x8 -> Bl[(t+1)&1]
//   I2: abh <- cvt(abf)=A(t+1)   [compiler wait vmcnt<=8 keeps B(t+1) in flight]
//   I3: issue A(t+2) -> abf (4x dwordx4)
//   C : 64 MFMA from Al(128x64) x Bl[t&1](512x64)
//   barrier
__global__ __launch_bounds__(512) __attribute__((amdgpu_waves_per_eu(2, 2)))
void gemm1_kernel(
    const float* __restrict__ A, const unsigned short* __restrict__ Bb,
    _Float16* __restrict__ part)
{
    __shared__ __align__(16) unsigned short Al[128 * 64];        // 16 KB
    __shared__ __align__(16) unsigned short Bl[2][512 * 64];     // 128 KB dbuf

    const int id = blockIdx.x;
    const int xcd = id & 7;
    const int g = id >> 3;           // 0..31
    const int mt = xcd * 8 + (g >> 2);  // 0..63
    const int z = g & 3;
    const int m0 = mt * 128;
    const int kbeg = z * 1024;
    const int NT = 16;

    const int tid = threadIdx.x;     // 0..511
    const int lane = tid & 63;
    const int wave = tid >> 6;       // 0..7
    const int wm = (wave >> 2) * 64;
    const int wn = (wave & 3) * 128;
    const int quad = lane >> 4;
    const int l16 = lane & 15;

    // A staging: 4 passes of 32 rows; row = p*32 + wave*4 + (lane>>4); q covers cols q*4..+3
    const int rowA = wave * 4 + (lane >> 4);
    const int q = lane & 15;
    const float* gA = A + (size_t)(m0 + rowA) * F_DIM + kbeg + q * 4;
    unsigned short* lw[4];
#pragma unroll
    for (int p = 0; p < 4; ++p) {
        const int r = rowA + p * 32;
        lw[p] = &Al[r * 64 + (((q >> 1) ^ (r & 7)) * 8) + (q & 1) * 4];
    }

    // B staging: 8 passes of 64 rows; row = p*64 + wave*8 + (lane>>3); granule = (lane&7)^dr
    const int drb = lane >> 3;
    const int cb = ((lane & 7) ^ drb) * 8;
    const unsigned short* gB = Bb + (size_t)(wave * 8 + drb) * F_DIM + kbeg + cb;
    const int lBoff = wave * 8 * 64;   // within-pass wave offset (shorts)

    const f32x4 zero = {0.f, 0.f, 0.f, 0.f};
    f32x4 acc[4][8];
#pragma unroll
    for (int i = 0; i < 4; ++i)
#pragma unroll
        for (int j2 = 0; j2 < 8; ++j2) acc[i][j2] = zero;

    f32x4 abf[4];     // fp32 A tile in flight
    uint2 abh[4];     // bf16 A tile, staged next

    // ---- prologue: B(0) async; A(0) -> regs -> cvt; issue A(1) ----
#pragma unroll
    for (int p = 0; p < 8; ++p)
        gload16(gB + (size_t)p * 64 * F_DIM, &Bl[0][p * 4096 + lBoff]);
    __builtin_amdgcn_sched_barrier(0);
#pragma unroll
    for (int p = 0; p < 4; ++p)
        abf[p] = *(const f32x4*)(gA + (size_t)p * 32 * F_DIM);
    __builtin_amdgcn_sched_barrier(0);
#pragma unroll
    for (int p = 0; p < 4; ++p) {      // cvt A(0); prologue-only full drain via reg-dep
        abh[p].x = pk2_hu(abf[p].x, abf[p].y);
        abh[p].y = pk2_hu(abf[p].z, abf[p].w);
    }
#pragma unroll
    for (int p = 0; p < 4; ++p)        // issue A(1)
        abf[p] = *(const f32x4*)(gA + 64 + (size_t)p * 32 * F_DIM);
    __builtin_amdgcn_sched_barrier(0);

    for (int t = 0; t < NT; ++t) {
        // S: stage A(t) (pure reg->LDS)
#pragma unroll
        for (int p = 0; p < 4; ++p)
            *(uint2*)lw[p] = abh[p];
        // W
        if (t < NT - 1) {
            asm volatile("s_waitcnt vmcnt(4) lgkmcnt(0)" ::: "memory");
        } else {
            asm volatile("s_waitcnt vmcnt(0) lgkmcnt(0)" ::: "memory");
        }
        __builtin_amdgcn_sched_barrier(0);
        __builtin_amdgcn_s_barrier();
        __builtin_amdgcn_sched_barrier(0);
        // I1: issue B(t+1)
        if (t + 1 < NT) {
#pragma unroll
            for (int p = 0; p < 8; ++p)
                gload16(gB + (size_t)(t + 1) * 64 + (size_t)p * 64 * F_DIM,
                        &Bl[(t + 1) & 1][p * 4096 + lBoff]);
        }
        __builtin_amdgcn_sched_barrier(0);
        // I2: cvt A(t+1); I3: issue A(t+2)
        if (t + 1 < NT) {
#pragma unroll
            for (int p = 0; p < 4; ++p) {
                abh[p].x = pk2_hu(abf[p].x, abf[p].y);
                abh[p].y = pk2_hu(abf[p].z, abf[p].w);
            }
        }
        if (t + 2 < NT) {
#pragma unroll
            for (int p = 0; p < 4; ++p)
                abf[p] = *(const f32x4*)(gA + (size_t)(t + 2) * 64
                                         + (size_t)p * 32 * F_DIM);
        }
        __builtin_amdgcn_sched_barrier(0);
        // C: compute tile t
        const unsigned short* Bcur = &Bl[t & 1][0];
#pragma unroll
        for (int kk = 0; kk < 64; kk += 32) {
            const int kb = kk + quad * 8;
            bf16x8 av[4];
#pragma unroll
            for (int i = 0; i < 4; ++i)
                av[i] = ldb(Al, wm + i * 16 + l16, kb);
#pragma unroll
            for (int j2 = 0; j2 < 8; ++j2) {
                const bf16x8 bv = ldb(Bcur, wn + j2 * 16 + l16, kb);
#pragma unroll
                for (int i = 0; i < 4; ++i)
                    acc[i][j2] = __builtin_amdgcn_mfma_f32_16x16x32_bf16(
                        av[i], bv, acc[i][j2], 0, 0, 0);
            }
        }
        __builtin_amdgcn_sched_barrier(0);
        __builtin_amdgcn_s_barrier();
        __builtin_amdgcn_sched_barrier(0);
    }

    _Float16* dst = part + (size_t)z * ((size_t)B_DIM * NL);
#pragma unroll
    for (int i = 0; i < 4; ++i) {
        const int mbase = m0 + wm + i * 16 + quad * 4;
#pragma unroll
        for (int j2 = 0; j2 < 8; ++j2) {
            const int n = wn + j2 * 16 + l16;
#pragma unroll
            for (int r = 0; r < 4; ++r)
                dst[(size_t)(mbase + r) * NL + n] = (_Float16)acc[i][j2][r];
        }
    }
}

// ---------------- fused reduce(fp16 partials) + bias + sigmoid + tree ----------------
__global__ __launch_bounds__(256) void reduce_tree_kernel(
    const _Float16* __restrict__ part, const float* __restrict__ bvec,
    unsigned short* __restrict__ leafbf)
{
    __shared__ float bsh[NL];
    __shared__ float prow[4][NL];

    const int tid = threadIdx.x;
    bsh[tid] = (tid < NI) ? bvec[tid] : 0.0f;
    const int t2 = tid + 256;
    bsh[t2] = (t2 < NI) ? bvec[t2] : 0.0f;

    const int wave = tid >> 6;
    const int lane = tid & 63;
    const int row = blockIdx.x * 4 + wave;
    const size_t base = (size_t)row * NL + lane * 8;

    float v[8] = {0.f, 0.f, 0.f, 0.f, 0.f, 0.f, 0.f, 0.f};
#pragma unroll
    for (int s = 0; s < SPLIT; ++s) {
        const f16x8 h = *(const f16x8*)(part + (size_t)s * ((size_t)B_DIM * NL) + base);
#pragma unroll
        for (int e = 0; e < 8; ++e) v[e] += (float)h[e];
    }
    __syncthreads();

#pragma unroll
    for (int i = 0; i < 8; ++i) {
        const float x = v[i] + bsh[lane * 8 + i];
        prow[wave][lane * 8 + i] = 1.0f / (1.0f + __expf(-x));
    }
    __syncthreads();

    const float* pr = prow[wave];
    float pre = 1.0f;
    int pnode = 0;
#pragma unroll
    for (int t = 5; t >= 0; --t) {
        const int bit = (lane >> t) & 1;
        const float p = pr[pnode];
        pre *= bit ? p : (1.0f - p);
        pnode = 2 * pnode + 1 + bit;
    }
    unsigned short outs[8];
#pragma unroll
    for (int jj = 0; jj < 8; ++jj) {
        float prob = pre;
        int node = pnode;
#pragma unroll
        for (int t = 2; t >= 0; --t) {
            const int bit = (jj >> t) & 1;
            const float p = pr[node];
            prob *= bit ? p : (1.0f - p);
            node = 2 * node + 1 + bit;
        }
        outs[jj] = f2bf(prob);
    }
    uint4 r;
    r.x = (unsigned int)outs[0] | ((unsigned int)outs[1] << 16);
    r.y = (unsigned int)outs[2] | ((unsigned int)outs[3] << 16);
    r.z = (unsigned int)outs[4] | ((unsigned int)outs[5] << 16);
    r.w = (unsigned int)outs[6] | ((unsigned int)outs[7] << 16);
    *(uint4*)(leafbf + (size_t)row * NL + lane * 8) = r;
}

// ---------------- GEMM2: out = leaf_prob @ dists, counted-vmcnt dbuf ----------------
// grid 512 = 8 xcd x 8 mhi x 8 nt; 64 KB LDS -> 2 blocks/CU even.
// Per iter: issue(t+1) -> vmcnt(8|0) -> barrier -> compute(t) -> barrier.
__global__ __launch_bounds__(256, 2) void gemm2_kernel(
    const unsigned short* __restrict__ A, const unsigned short* __restrict__ Bm,
    float* __restrict__ out)
{
    __shared__ __align__(16) unsigned short Al[2][128 * 64];    // 32 KB
    __shared__ __align__(16) unsigned short Bl[2][128 * 64];    // 32 KB

    const int id = blockIdx.x;
    const int xcd = id & 7;
    const int j = id >> 3;
    const int nt = j & 7;
    const int mhi = j >> 3;
    const int m0 = (mhi * 8 + xcd) * 128;
    const int n0 = nt * 128;

    const int tid = threadIdx.x;
    const int lane = tid & 63;
    const int wave = tid >> 6;
    const int wm = (wave >> 1) * 64;
    const int wn = (wave & 1) * 64;
    const int quad = lane >> 4;
    const int l16 = lane & 15;

    const int drb = lane >> 3;
    const int cb = ((lane & 7) ^ drb) * 8;
    const unsigned short* gA = A + (size_t)(m0 + wave * 8 + drb) * NL + cb;
    const unsigned short* gB = Bm + (size_t)(n0 + wave * 8 + drb) * NL + cb;
    const int loff = wave * 8 * 64;

    const f32x4 zero = {0.f, 0.f, 0.f, 0.f};
    f32x4 acc[4][4];
#pragma unroll
    for (int i = 0; i < 4; ++i)
#pragma unroll
        for (int j2 = 0; j2 < 4; ++j2) acc[i][j2] = zero;

    // prologue: issue tile 0
#pragma unroll
    for (int p = 0; p < 4; ++p) {
        gload16(gA + (size_t)p * 32 * NL, &Al[0][loff + p * 2048]);
        gload16(gB + (size_t)p * 32 * NL, &Bl[0][loff + p * 2048]);
    }
    __builtin_amdgcn_sched_barrier(0);

#pragma unroll
    for (int t = 0; t < 8; ++t) {
        if (t + 1 < 8) {
#pragma unroll
            for (int p = 0; p < 4; ++p) {
                gload16(gA + (size_t)(t + 1) * 64 + (size_t)p * 32 * NL,
                        &Al[(t + 1) & 1][loff + p * 2048]);
                gload16(gB + (size_t)(t + 1) * 64 + (size_t)p * 32 * NL,
                        &Bl[(t + 1) & 1][loff + p * 2048]);
            }
            __builtin_amdgcn_sched_barrier(0);
            asm volatile("s_waitcnt vmcnt(8)" ::: "memory");
        } else {
            __builtin_amdgcn_sched_barrier(0);
            asm volatile("s_waitcnt vmcnt(0)" ::: "memory");
        }
        __builtin_amdgcn_sched_barrier(0);
        __builtin_amdgcn_s_barrier();
        __builtin_amdgcn_sched_barrier(0);
#pragma unroll
        for (int kk = 0; kk < 64; kk += 32) {
            const int kb = kk + quad * 8;
            bf16x8 av[4], bv[4];
#pragma unroll
            for (int i = 0; i < 4; ++i)
                av[i] = ldb(&Al[t & 1][0], wm + i * 16 + l16, kb);
#pragma unroll
            for (int j2 = 0; j2 < 4; ++j2)
                bv[j2] = ldb(&Bl[t & 1][0], wn + j2 * 16 + l16, kb);
#pragma unroll
            for (int i = 0; i < 4; ++i)
#pragma unroll
                for (int j2 = 0; j2 < 4; ++j2)
                    acc[i][j2] = __builtin_amdgcn_mfma_f32_16x16x32_bf16(av[i], bv[j2], acc[i][j2], 0, 0, 0);
        }
        __builtin_amdgcn_sched_barrier(0);
        __builtin_amdgcn_s_barrier();
        __builtin_amdgcn_sched_barrier(0);
    }

#pragma unroll
    for (int i = 0; i < 4; ++i) {
        const int mbase = m0 + wm + i * 16 + quad * 4;
#pragma unroll
        for (int j2 = 0; j2 < 4; ++j2) {
            const int n = n0 + wn + j2 * 16 + l16;
            if (n < K_DIM) {
#pragma unroll
                for (int r = 0; r < 4; ++r)
                    out[(size_t)(mbase + r) * K_DIM + n] = acc[i][j2][r];
            }
        }
    }
}

extern "C" void kernel_launch(void* const* d_in, const int* in_sizes, int n_in,
                              void* d_out, int out_size, void* d_ws, size_t ws_size,
                              hipStream_t stream) {
    const float* xs = (const float*)d_in[0];
    const float* W  = (const float*)d_in[1];
    const float* b  = (const float*)d_in[2];
    const float* lp = (const float*)d_in[3];
    float* out = (float*)d_out;

    const size_t partB = (size_t)B_DIM * NL * 2;   //  8 MiB per slice (fp16)
    const size_t leafB = (size_t)B_DIM * NL * 2;   //  8 MiB
    const size_t dTB   = (size_t)KPAD * NL * 2;    //  1 MiB

    char* ws = (char*)d_ws;
    _Float16* part = (_Float16*)ws;
    unsigned short* leafbf = (unsigned short*)(ws + SPLIT * partB);
    unsigned short* dT = (unsigned short*)(ws + SPLIT * partB + leafB);
    unsigned short* Wb = (unsigned short*)(ws + SPLIT * partB + leafB + dTB);
    (void)ws_size;  // needs ~45 MiB; harness provides 512 MiB

    hipLaunchKernelGGL(prep_kernel, dim3(W_BLKS + SM_BLKS), dim3(256), 0, stream,
                       W, Wb, lp, dT);
    hipLaunchKernelGGL(gemm1_kernel, dim3(256), dim3(512), 0, stream,
                       xs, Wb, part);
    hipLaunchKernelGGL(reduce_tree_kernel, dim3(B_DIM / 4), dim3(256), 0, stream,
                       part, b, leafbf);
    hipLaunchKernelGGL(gemm2_kernel, dim3(8 * 8 * 8), dim3(256), 0, stream,
                       leafbf, dT, out);
}